// Round 12
// baseline (560.072 us; speedup 1.0000x reference)
//
#include <hip/hip_runtime.h>
#include <stdint.h>

// ---------------------------------------------------------------------------
// NIVR: coord-MLP over 512x512 grid.
//   time_kernel: time branch -> tvec[512] (fp32-exact, 1 block)
//   pre_kernel:  posenc tables (+tvec folded) -> Txp, Ty; W2f -> bf16
//                frag-swizzled W2s.
//   main: PRODUCER/CONSUMER wave specialization (hipBLASLt pattern).
//     waves 0-3 (producers): compute h1=relu(Txp[x]+Ty[y]) -> bf16 A-slabs
//       into LDS (dbuf, 32KB halves) + layer3 sum/store of previous tile.
//     waves 4-7 (consumers): own 128 cols each; pure K-loop: 8 B-loads +
//       4 ds_reads + 32 MFMA per step, ZERO VALU; acc=128 AGPR.
//   8 tiles (64px) per block; barrier per half-tile; 18 intervals/block.
//
// Rationale: R5-plateau cycle audit (561K cyc/CU) shows the serial per-wave
// chain load->ds->MFMA sums (MFMA 159K + DS 98K + VMEM 196K + VALU 100K)
// with no overlap; identical-wave scheduling tweaks (R6/R9/R10) never fixed
// it. Role-split puts each pipe's work on different waves => m114 overlap.
// ---------------------------------------------------------------------------

typedef short bf16x8 __attribute__((ext_vector_type(8)));
typedef float f32x4 __attribute__((ext_vector_type(4)));

#define PI_F 3.14159265358979323846f
#define SIDE 512
#define NPIX (SIDE * SIDE)
#define T_TILES 8

__device__ __forceinline__ unsigned short f2bf(float f) {
  unsigned int u = __float_as_uint(f);
  u += 0x7fffu + ((u >> 16) & 1u);
  return (unsigned short)(u >> 16);
}

// ---------------------------------------------------------------------------
// time branch (exact fp32), 1 block x 512 threads -> tvec[512]
// ---------------------------------------------------------------------------
__global__ void time_kernel(const float* __restrict__ W1p, const float* __restrict__ b1p,
                            const float* __restrict__ W2p, const float* __restrict__ b2p,
                            const float* __restrict__ W1f, const float* __restrict__ b1f,
                            const int* __restrict__ idx, float* __restrict__ tvec) {
  __shared__ float r_s[32];
  __shared__ float h_s[256];
  __shared__ float phi_s[128];
  const int t = threadIdx.x;
  if (t < 16) {
    float tt = (float)idx[0] / 300.0f;
    float ang = tt * ldexpf(PI_F, t);
    r_s[t] = sinf(ang);
    r_s[16 + t] = cosf(ang);
  }
  __syncthreads();
  if (t < 256) {
    float a = b1p[t];
#pragma unroll
    for (int i = 0; i < 32; ++i) a += r_s[i] * W1p[i * 256 + t];
    h_s[t] = fmaxf(a, 0.f);
  }
  __syncthreads();
  if (t < 128) {
    float a = b2p[t];
    for (int i = 0; i < 256; ++i) a += h_s[i] * W2p[i * 128 + t];
    phi_s[t] = a;
  }
  __syncthreads();
  {
    float a = b1f[t];
    for (int p = 0; p < 128; ++p) a += phi_s[p] * W1f[(40 + p) * 512 + t];
    tvec[t] = a;
  }
}

// ---------------------------------------------------------------------------
// pre_kernel: 1024 blocks x 512 threads.
//   blocks 0..511: Txp[v][k] = tvec[k] + sum_l enc[l] W1f[l][k];
//                  Ty [v][k] = sum_l enc[l] W1f[20+l][k]
//   blocks 512..1023: W2f -> bf16 swizzle:
//     W2s[ks*16384 + nt*512 + q*128 + ni*8 + j] = bf16(W2f[ks*32+q*8+j][nt*16+ni])
// ---------------------------------------------------------------------------
__global__ void pre_kernel(const float* __restrict__ W1f, const float* __restrict__ W2f,
                           const float* __restrict__ tvec, float* __restrict__ Txp,
                           float* __restrict__ Ty, unsigned short* __restrict__ W2s) {
  const int b = blockIdx.x;
  const int t = threadIdx.x;

  if (b >= 512) {
    const int k = b - 512, n = t;
    const int ks = k >> 5, q = (k >> 3) & 3, j = k & 7;
    const int nt = n >> 4, ni = n & 15;
    W2s[ks * 16384 + nt * 512 + q * 128 + ni * 8 + j] = f2bf(W2f[k * 512 + n]);
    return;
  }

  __shared__ float enc[20];
  if (t < 10) {
    float u = (float)b / 512.0f;
    float ang = u * ldexpf(PI_F, t);
    enc[t] = sinf(ang);
    enc[10 + t] = cosf(ang);
  }
  __syncthreads();
  float ax = tvec[t], ay = 0.f;
#pragma unroll
  for (int l = 0; l < 20; ++l) {
    ax += enc[l] * W1f[l * 512 + t];
    ay += enc[l] * W1f[(20 + l) * 512 + t];
  }
  Txp[b * 512 + t] = ax;
  Ty[b * 512 + t] = ay;
}

// ---------------------------------------------------------------------------
// Main kernel. Grid (64, 8) x 512 threads. Block (px, by) handles tiles
// tt = 0..7: 8x8 pixel patch at (px*8, (by*8+tt)*8). BM=64, BN=512, K=512.
//
// Interval schedule (i = 0 .. 17; hs = half-slot = tile*2 + half):
//   producers (waves 0-3, 256 thr): if i<16: fill hs=i into Ab[i&1]
//                                    if i odd && i>=3: sum/store part((i-3)/2)
//   consumers (waves 4-7):          if 1<=i<=16: crunch hs=i-1 from Ab[(i-1)&1]
//                                    (zero acc at half 0; part-write at half 1)
//   __syncthreads() per interval.
// LDS: Ab[2][8 slabs x 2048 shorts] = 64KB + part[4][64][3] = 3KB.
// ---------------------------------------------------------------------------
__global__ __launch_bounds__(512, 2) void main_kernel(
    const float* __restrict__ Txp, const float* __restrict__ Ty,
    const unsigned short* __restrict__ W2s, const float* __restrict__ b2f,
    const float* __restrict__ W3f, const float* __restrict__ b3f,
    float* __restrict__ out) {
  __shared__ __attribute__((aligned(16))) unsigned short Ab[2][8 * 2048];  // 64KB
  __shared__ float part[4][64][3];                                         // 3KB

  const int t = threadIdx.x;
  const int w = t >> 6;
  const int lane = t & 63;
  const int q = lane >> 4;
  const int lr = lane & 15;
  const int px = blockIdx.x, by = blockIdx.y;
  const int x0 = px * 8;

  // ---- producer mapping (waves 0-3, thread p = t in [0,256)) ----
  const int v = t & 255;
  const int pp = ((v >> 6) << 4) + (v & 15);  // pixel 0..63
  const int q2 = (v >> 4) & 3;                // k-quad within 32-step
  const int xi = x0 + (pp >> 3);
  const float* txp = Txp + xi * 512 + q2 * 8;

  // ---- consumer state (waves 4-7) ----
  const int wc = w - 4;                        // 0..3, owns cols wc*128
  const unsigned short* bptr = W2s + lane * 8; // + ks*16384 + nt*512
  const int nt0 = wc * 8;

  f32x4 acc[4][8];
  bf16x8 bbank[2][8];
  bf16x8 areg[2][4];

  if (w >= 4) {
    // preload B(ks=0) into bank 0
#pragma unroll
    for (int j = 0; j < 8; ++j)
      bbank[0][j] = *(const bf16x8*)(bptr + 0 * 16384 + (nt0 + j) * 512);
  }

#pragma unroll 1
  for (int i = 0; i < 2 * T_TILES + 2; ++i) {
    if (w < 4) {
      // ================= PRODUCER =================
      if (i < 2 * T_TILES) {
        const int hs = i, tt = hs >> 1, hf = hs & 1, buf = hs & 1;
        const int yi = (by * 8 + tt) * 8 + (pp & 7);
        const float* typ = Ty + yi * 512 + q2 * 8;
#pragma unroll
        for (int sl = 0; sl < 8; ++sl) {
          const int ko = (hf * 8 + sl) * 32 + 0;  // +q2*8 already in ptrs
          float4 a0 = *(const float4*)(txp + ko);
          float4 a1 = *(const float4*)(txp + ko + 4);
          float4 b0 = *(const float4*)(typ + ko);
          float4 b1 = *(const float4*)(typ + ko + 4);
          uint4 pk;
          pk.x = (unsigned)f2bf(fmaxf(a0.x + b0.x, 0.f)) |
                 ((unsigned)f2bf(fmaxf(a0.y + b0.y, 0.f)) << 16);
          pk.y = (unsigned)f2bf(fmaxf(a0.z + b0.z, 0.f)) |
                 ((unsigned)f2bf(fmaxf(a0.w + b0.w, 0.f)) << 16);
          pk.z = (unsigned)f2bf(fmaxf(a1.x + b1.x, 0.f)) |
                 ((unsigned)f2bf(fmaxf(a1.y + b1.y, 0.f)) << 16);
          pk.w = (unsigned)f2bf(fmaxf(a1.z + b1.z, 0.f)) |
                 ((unsigned)f2bf(fmaxf(a1.w + b1.w, 0.f)) << 16);
          *(uint4*)&Ab[buf][sl * 2048 + v * 8] = pk;
        }
      }
      // layer-3 sum/store of tile (i-3)/2 (part published at interval i-1)
      if ((i & 1) && i >= 3 && t < 192) {
        const int tt2 = (i - 3) >> 1;
        const int c = t >> 6, mm = t & 63;
        float sum = b3f[c];
#pragma unroll
        for (int ww = 0; ww < 4; ++ww) sum += part[ww][mm][c];
        const int n = (x0 + (mm >> 3)) * 512 + (by * 8 + tt2) * 8 + (mm & 7);
        out[c * NPIX + n] = sum;
      }
    } else {
      // ================= CONSUMER =================
      if (i >= 1 && i <= 2 * T_TILES) {
        const int hs = i - 1, hf = hs & 1, buf = hs & 1;
        const int kb = hf * 8;
        if (hf == 0) {
#pragma unroll
          for (int mi = 0; mi < 4; ++mi)
#pragma unroll
            for (int j = 0; j < 8; ++j) acc[mi][j] = (f32x4){0.f, 0.f, 0.f, 0.f};
        }
        // A prologue for step 0
#pragma unroll
        for (int mt = 0; mt < 4; ++mt)
          areg[0][mt] = *(const bf16x8*)&Ab[buf][mt * 512 + lane * 8];
#pragma unroll
        for (int s = 0; s < 8; ++s) {
          if (s < 7) {
#pragma unroll
            for (int mt = 0; mt < 4; ++mt)
              areg[(s + 1) & 1][mt] =
                  *(const bf16x8*)&Ab[buf][(s + 1) * 2048 + mt * 512 + lane * 8];
          }
          // B prefetch for next step (crosses interval at s==7)
          const int nks = (s < 7) ? (kb + s + 1) : (kb ^ 8);
#pragma unroll
          for (int j = 0; j < 8; ++j)
            bbank[(s + 1) & 1][j] =
                *(const bf16x8*)(bptr + nks * 16384 + (nt0 + j) * 512);
          // 32 MFMAs for step s
#pragma unroll
          for (int j = 0; j < 8; ++j)
#pragma unroll
            for (int mt = 0; mt < 4; ++mt)
              acc[mt][j] = __builtin_amdgcn_mfma_f32_16x16x32_bf16(
                  areg[s & 1][mt], bbank[s & 1][j], acc[mt][j], 0, 0, 0);
        }
        if (hf == 1) {
          // epilogue: h2=relu(acc+b2f); rgb partials over this wave's 128 cols
#pragma unroll
          for (int pass = 0; pass < 2; ++pass) {
            float vv[2][4][3];
#pragma unroll
            for (int mi = 0; mi < 2; ++mi)
#pragma unroll
              for (int r = 0; r < 4; ++r)
#pragma unroll
                for (int cc = 0; cc < 3; ++cc) vv[mi][r][cc] = 0.f;
#pragma unroll
            for (int mi = 0; mi < 2; ++mi) {
              const int mt = pass * 2 + mi;
#pragma unroll
              for (int j = 0; j < 8; ++j) {
                const int k = wc * 128 + j * 16 + lr;
                const float b2 = b2f[k];
                const float w30 = W3f[k * 3 + 0];
                const float w31 = W3f[k * 3 + 1];
                const float w32 = W3f[k * 3 + 2];
#pragma unroll
                for (int r = 0; r < 4; ++r) {
                  float h2 = fmaxf(acc[mt][j][r] + b2, 0.f);
                  vv[mi][r][0] += h2 * w30;
                  vv[mi][r][1] += h2 * w31;
                  vv[mi][r][2] += h2 * w32;
                }
              }
            }
#pragma unroll
            for (int d = 1; d < 16; d <<= 1) {
#pragma unroll
              for (int mi = 0; mi < 2; ++mi)
#pragma unroll
                for (int r = 0; r < 4; ++r)
#pragma unroll
                  for (int cc = 0; cc < 3; ++cc)
                    vv[mi][r][cc] += __shfl_xor(vv[mi][r][cc], d, 64);
            }
            if (lr == 0) {
#pragma unroll
              for (int mi = 0; mi < 2; ++mi)
#pragma unroll
                for (int r = 0; r < 4; ++r) {
                  const int row = (pass * 2 + mi) * 16 + q * 4 + r;
#pragma unroll
                  for (int cc = 0; cc < 3; ++cc) part[wc][row][cc] = vv[mi][r][cc];
                }
            }
          }
        }
      }
    }
    __syncthreads();
  }
}

// ---------------------------------------------------------------------------
// Inputs: 0 coords (unused), 1 W1p, 2 b1p, 3 W2p, 4 b2p, 5 W1f, 6 b1f,
//         7 W2f, 8 b2f, 9 W3f, 10 b3f, 11 idx
// ---------------------------------------------------------------------------
extern "C" void kernel_launch(void* const* d_in, const int* in_sizes, int n_in,
                              void* d_out, int out_size, void* d_ws, size_t ws_size,
                              hipStream_t stream) {
  const float* W1p = (const float*)d_in[1];
  const float* b1p = (const float*)d_in[2];
  const float* W2p = (const float*)d_in[3];
  const float* b2p = (const float*)d_in[4];
  const float* W1f = (const float*)d_in[5];
  const float* b1f = (const float*)d_in[6];
  const float* W2f = (const float*)d_in[7];
  const float* b2f = (const float*)d_in[8];
  const float* W3f = (const float*)d_in[9];
  const float* b3f = (const float*)d_in[10];
  const int* idx = (const int*)d_in[11];
  float* out = (float*)d_out;

  char* ws = (char*)d_ws;
  float* Txp = (float*)ws;                                   // 1 MB
  float* Ty = (float*)(ws + (1u << 20));                     // 1 MB
  unsigned short* W2s = (unsigned short*)(ws + (2u << 20));  // 512 KB
  float* tvec = (float*)(ws + (2u << 20) + (512u << 10));    // 2 KB

  hipLaunchKernelGGL(time_kernel, dim3(1), dim3(512), 0, stream,
                     W1p, b1p, W2p, b2p, W1f, b1f, idx, tvec);
  hipLaunchKernelGGL(pre_kernel, dim3(1024), dim3(512), 0, stream,
                     W1f, W2f, tvec, Txp, Ty, W2s);
  hipLaunchKernelGGL(main_kernel, dim3(64, 8), dim3(512), 0, stream,
                     Txp, Ty, W2s, b2f, W3f, b3f, out);
}

// Round 13
// 292.253 us; speedup vs baseline: 1.9164x; 1.9164x over previous
//
#include <hip/hip_runtime.h>
#include <stdint.h>

// ---------------------------------------------------------------------------
// NIVR: coord-MLP over 512x512 grid.
//   pre_kernel (fused, R8-verified): posenc tables with time branch folded
//     -> Txp (=Tx+tvec), Ty; W2f -> bf16 frag-swizzled W2s. 1 launch.
//   main_kernel (R9-verbatim, best measured 232.2us): h1=relu(Txp[x]+Ty[y]);
//     layer2 via MFMA bf16 16x16x32, A-tile LDS-resident, B depth-2 register
//     pipeline, no K-loop barriers; fused layer3 epilogue. Output [3][N].
//
// R13 = consolidation. 12-round evidence: main plateau 232-243us across five
// structures; all pipes <50% utilized; scheduling interventions (chunk
// overlap, deeper prefetch, K-rotation, weight-stationary, producer/consumer)
// neutral or regressive — the two clean ones land exactly on the plateau.
// Any wave needing >~210 live regs spills (R7/R11/R12). So: take the best
// measured main verbatim (R9) and cut fixed overhead (3 launches -> 2; pre
// recomputes the tiny time-MLP per table block, fp32-exact, R8-verified).
// ---------------------------------------------------------------------------

typedef short bf16x8 __attribute__((ext_vector_type(8)));
typedef float f32x4 __attribute__((ext_vector_type(4)));

#define PI_F 3.14159265358979323846f
#define SIDE 512
#define NPIX (SIDE * SIDE)

__device__ __forceinline__ unsigned short f2bf(float f) {
  unsigned int u = __float_as_uint(f);
  u += 0x7fffu + ((u >> 16) & 1u);
  return (unsigned short)(u >> 16);
}

// ---------------------------------------------------------------------------
// Fused precompute kernel (R8-verified). Grid = 1024 blocks x 512 threads:
//   blocks 0..511  : posenc tables for coord v=b, time branch folded:
//                    Txp[v][k] = tvec[k] + sum_l enc[l] W1f[l][k]
//                    Ty [v][k] =           sum_l enc[l] W1f[20+l][k]
//                    (tvec recomputed redundantly per block; deterministic)
//   blocks 512..1023: W2f -> bf16 frag-swizzled W2s (k-row = b-512)
// W2s layout: id = ks*16384 + nt*512 + q*128 + ni*8 + j  (shorts)
//   W2s[id] = bf16(W2f[ks*32 + q*8 + j][nt*16 + ni])
// ---------------------------------------------------------------------------
__global__ void pre_kernel(const float* __restrict__ W1p, const float* __restrict__ b1p,
                           const float* __restrict__ W2p, const float* __restrict__ b2p,
                           const float* __restrict__ W1f, const float* __restrict__ b1f,
                           const float* __restrict__ W2f, const int* __restrict__ idx,
                           float* __restrict__ Txp, float* __restrict__ Ty,
                           unsigned short* __restrict__ W2s) {
  const int b = blockIdx.x;
  const int t = threadIdx.x;

  if (b >= 512) {
    const int k = b - 512, n = t;
    const int ks = k >> 5, q = (k >> 3) & 3, j = k & 7;
    const int nt = n >> 4, ni = n & 15;
    W2s[ks * 16384 + nt * 512 + q * 128 + ni * 8 + j] = f2bf(W2f[k * 512 + n]);
    return;
  }

  __shared__ float enc[20];
  __shared__ float r_s[32];
  __shared__ float h_s[256];
  __shared__ float phi_s[128];

  if (t < 10) {
    float u = (float)b / 512.0f;
    float ang = u * ldexpf(PI_F, t);
    enc[t] = sinf(ang);
    enc[10 + t] = cosf(ang);
  }
  if (t >= 32 && t < 48) {
    const int l = t - 32;
    float tt = (float)idx[0] / 300.0f;
    float ang = tt * ldexpf(PI_F, l);
    r_s[l] = sinf(ang);
    r_s[16 + l] = cosf(ang);
  }
  __syncthreads();
  if (t < 256) {
    float a = b1p[t];
#pragma unroll
    for (int i = 0; i < 32; ++i) a += r_s[i] * W1p[i * 256 + t];
    h_s[t] = fmaxf(a, 0.f);
  }
  __syncthreads();
  if (t < 128) {
    float a = b2p[t];
    for (int i = 0; i < 256; ++i) a += h_s[i] * W2p[i * 128 + t];
    phi_s[t] = a;
  }
  __syncthreads();
  {
    float tv = b1f[t];
    for (int p = 0; p < 128; ++p) tv += phi_s[p] * W1f[(40 + p) * 512 + t];
    float ax = tv, ay = 0.f;
#pragma unroll
    for (int l = 0; l < 20; ++l) {
      ax += enc[l] * W1f[l * 512 + t];
      ay += enc[l] * W1f[(20 + l) * 512 + t];
    }
    Txp[b * 512 + t] = ax;
    Ty[b * 512 + t] = ay;
  }
}

// ---------------------------------------------------------------------------
// Main fused kernel (R9-verbatim, 232.2us). Block = 512 thr (8 waves),
// BM=64 (8x8 patch), BN=512, K=512 in 16 steps of 32. Wave w owns N-slice
// [w*64, w*64+64). A tile 64KB LDS-resident; B depth-2 register pipeline.
// ---------------------------------------------------------------------------
__global__ __launch_bounds__(512, 2) void main_kernel(
    const float* __restrict__ Txp, const float* __restrict__ Ty,
    const unsigned short* __restrict__ W2s, const float* __restrict__ b2f,
    const float* __restrict__ W3f, const float* __restrict__ b3f,
    float* __restrict__ out) {
  __shared__ __attribute__((aligned(16))) unsigned short Ab[16 * 2048];  // 64KB
  __shared__ float part[8][64][3];                                       // 6KB

  const int t = threadIdx.x;
  const int w = t >> 6;            // wave id 0..7  (N-slice)
  const int lane = t & 63;
  const int q = lane >> 4;
  const int lr = lane & 15;
  const int x0 = blockIdx.x * 8, y0 = blockIdx.y * 8;

  // B: wave w owns nt-slots w*4..w*4+3; frag (ks,nt) at +ks*16384 + nt*512;
  // lane reads at +lane*8 (16B, coalesced 1KB/wave).
  const unsigned short* bptr = W2s + (w * 4) * 512 + lane * 8;

  // ---- B pipeline: depth 2. breg[ks%3] used at step ks. ----
  bf16x8 breg[3][4];
#pragma unroll
  for (int nt = 0; nt < 4; ++nt) {
    breg[0][nt] = *(const bf16x8*)(bptr + 0 * 16384 + nt * 512);
    breg[1][nt] = *(const bf16x8*)(bptr + 1 * 16384 + nt * 512);
  }

  // ---- A fill (once): thread (p = t>>3, s = t&7) covers pixel p,
  // k = ks*32 + s*4..+3; frag slot abase.
  {
    const int p = t >> 3, s = t & 7;
    const int xi = x0 + (p >> 3), yi = y0 + (p & 7);
    const float* txp = Txp + xi * 512 + s * 4;
    const float* typ = Ty + yi * 512 + s * 4;
    const int abase = (((p >> 4) * 4 + (s >> 1)) * 16 + (p & 15)) * 8 + (s & 1) * 4;
#pragma unroll
    for (int ks = 0; ks < 16; ++ks) {
      float4 a = *(const float4*)(txp + ks * 32);
      float4 b = *(const float4*)(typ + ks * 32);
      uint2 pk;
      pk.x = (unsigned)f2bf(fmaxf(a.x + b.x, 0.f)) |
             ((unsigned)f2bf(fmaxf(a.y + b.y, 0.f)) << 16);
      pk.y = (unsigned)f2bf(fmaxf(a.z + b.z, 0.f)) |
             ((unsigned)f2bf(fmaxf(a.w + b.w, 0.f)) << 16);
      *(uint2*)&Ab[ks * 2048 + abase] = pk;
    }
  }

  f32x4 acc[4][4];
#pragma unroll
  for (int i = 0; i < 4; ++i)
#pragma unroll
    for (int j2 = 0; j2 < 4; ++j2) acc[i][j2] = (f32x4){0.f, 0.f, 0.f, 0.f};

  __syncthreads();  // publishes A; the only barrier before the epilogue

  // ---- A-frag pipeline: depth 1. areg[ks&1] used at step ks. ----
  bf16x8 areg[2][4];
#pragma unroll
  for (int mt = 0; mt < 4; ++mt)
    areg[0][mt] = *(const bf16x8*)&Ab[0 * 2048 + mt * 512 + lane * 8];

  // ---- K-loop, fully unrolled, no barriers, no register copies ----
#pragma unroll
  for (int ks = 0; ks < 16; ++ks) {
    if (ks + 2 < 16) {
#pragma unroll
      for (int nt = 0; nt < 4; ++nt)
        breg[(ks + 2) % 3][nt] =
            *(const bf16x8*)(bptr + (ks + 2) * 16384 + nt * 512);
    }
    if (ks + 1 < 16) {
#pragma unroll
      for (int mt = 0; mt < 4; ++mt)
        areg[(ks + 1) & 1][mt] =
            *(const bf16x8*)&Ab[(ks + 1) * 2048 + mt * 512 + lane * 8];
    }
#pragma unroll
    for (int nt = 0; nt < 4; ++nt)
#pragma unroll
      for (int mt = 0; mt < 4; ++mt)
        acc[mt][nt] = __builtin_amdgcn_mfma_f32_16x16x32_bf16(
            areg[ks & 1][mt], breg[ks % 3][nt], acc[mt][nt], 0, 0, 0);
  }

  // ---- epilogue: h2 = relu(acc + b2f); rgb partial = h2 @ W3f (k-slice) ----
  float w3v[4][3];
  float bb2[4];
#pragma unroll
  for (int nt = 0; nt < 4; ++nt) {
    const int k = w * 64 + nt * 16 + lr;
    bb2[nt] = b2f[k];
    w3v[nt][0] = W3f[k * 3 + 0];
    w3v[nt][1] = W3f[k * 3 + 1];
    w3v[nt][2] = W3f[k * 3 + 2];
  }
#pragma unroll
  for (int half = 0; half < 2; ++half) {
    float vv[2][4][3];
#pragma unroll
    for (int mi = 0; mi < 2; ++mi)
#pragma unroll
      for (int r = 0; r < 4; ++r)
#pragma unroll
        for (int cc = 0; cc < 3; ++cc) vv[mi][r][cc] = 0.f;
#pragma unroll
    for (int mi = 0; mi < 2; ++mi) {
      const int mt = half * 2 + mi;
#pragma unroll
      for (int r = 0; r < 4; ++r) {
#pragma unroll
        for (int nt = 0; nt < 4; ++nt) {
          float h2 = fmaxf(acc[mt][nt][r] + bb2[nt], 0.f);
          vv[mi][r][0] += h2 * w3v[nt][0];
          vv[mi][r][1] += h2 * w3v[nt][1];
          vv[mi][r][2] += h2 * w3v[nt][2];
        }
      }
    }
#pragma unroll
    for (int d = 1; d < 16; d <<= 1) {
#pragma unroll
      for (int mi = 0; mi < 2; ++mi)
#pragma unroll
        for (int r = 0; r < 4; ++r)
#pragma unroll
          for (int cc = 0; cc < 3; ++cc)
            vv[mi][r][cc] += __shfl_xor(vv[mi][r][cc], d, 64);
    }
    if (lr == 0) {
#pragma unroll
      for (int mi = 0; mi < 2; ++mi)
#pragma unroll
        for (int r = 0; r < 4; ++r) {
          const int row = (half * 2 + mi) * 16 + q * 4 + r;
#pragma unroll
          for (int cc = 0; cc < 3; ++cc) part[w][row][cc] = vv[mi][r][cc];
        }
    }
  }
  __syncthreads();
  if (t < 192) {
    const int c = t >> 6, mm = t & 63;
    float sum = b3f[c];
#pragma unroll
    for (int ww = 0; ww < 8; ++ww) sum += part[ww][mm][c];
    const int n = (x0 + (mm >> 3)) * 512 + (y0 + (mm & 7));
    out[c * NPIX + n] = sum;
  }
}

// ---------------------------------------------------------------------------
// Inputs: 0 coords (unused), 1 W1p, 2 b1p, 3 W2p, 4 b2p, 5 W1f, 6 b1f,
//         7 W2f, 8 b2f, 9 W3f, 10 b3f, 11 idx
// ---------------------------------------------------------------------------
extern "C" void kernel_launch(void* const* d_in, const int* in_sizes, int n_in,
                              void* d_out, int out_size, void* d_ws, size_t ws_size,
                              hipStream_t stream) {
  const float* W1p = (const float*)d_in[1];
  const float* b1p = (const float*)d_in[2];
  const float* W2p = (const float*)d_in[3];
  const float* b2p = (const float*)d_in[4];
  const float* W1f = (const float*)d_in[5];
  const float* b1f = (const float*)d_in[6];
  const float* W2f = (const float*)d_in[7];
  const float* b2f = (const float*)d_in[8];
  const float* W3f = (const float*)d_in[9];
  const float* b3f = (const float*)d_in[10];
  const int* idx = (const int*)d_in[11];
  float* out = (float*)d_out;

  char* ws = (char*)d_ws;
  float* Txp = (float*)ws;                                   // 1 MB
  float* Ty = (float*)(ws + (1u << 20));                     // 1 MB
  unsigned short* W2s = (unsigned short*)(ws + (2u << 20));  // 512 KB

  hipLaunchKernelGGL(pre_kernel, dim3(1024), dim3(512), 0, stream,
                     W1p, b1p, W2p, b2p, W1f, b1f, W2f, idx, Txp, Ty, W2s);
  hipLaunchKernelGGL(main_kernel, dim3(64, 64), dim3(512), 0, stream,
                     Txp, Ty, W2s, b2f, W3f, b3f, out);
}